// Round 10
// baseline (170.833 us; speedup 1.0000x reference)
//
#include <hip/hip_runtime.h>
#include <hip/hip_bf16.h>

typedef __attribute__((ext_vector_type(8))) short short8;   // 8 bf16 (4 VGPRs)
typedef __attribute__((ext_vector_type(4))) float floatx4;  // MFMA C/D

// (B,T,D) = (128,1024,64) fp32. out[i][j][t] = prod_{s<=t}(1 + <dX(s-1),dY(s-1)>/dt)
constexpr int BX    = 128;
constexpr int TT    = 1024;
constexpr int DDIM  = 64;
constexpr int NPAIR = BX * BX;
constexpr int LCH   = 16;              // t-steps per block
constexpr int NCH   = TT / LCH;        // 64
constexpr float DT_INV = 1023.0f;

// LDS element index for bf16 rows of 64 with XOR-segment swizzle (16B segments).
__device__ __forceinline__ int sidxE(int row, int k) {
    return row * 64 + ((((k >> 3) ^ (row & 7)) << 3) | (k & 7));
}

__device__ __forceinline__ ushort f2bf(float f) {           // round-to-nearest-even bf16
    uint u = __builtin_bit_cast(uint, f);
    u += 0x7fffu + ((u >> 16) & 1u);
    return (ushort)(u >> 16);
}

// 8 floats -> hi/lo bf16 split via packed bf16 converts, two 16B LDS stores.
__device__ __forceinline__ void cvt_store(ushort* hiP, ushort* loP, const float* v) {
    uint hw[4], lw[4];
#pragma unroll
    for (int p = 0; p < 4; ++p) {
        const __hip_bfloat162 h = __float22bfloat162_rn(make_float2(v[2 * p], v[2 * p + 1]));
        const float r0 = v[2 * p]     - __bfloat162float(h.x);
        const float r1 = v[2 * p + 1] - __bfloat162float(h.y);
        const __hip_bfloat162 l = __float22bfloat162_rn(make_float2(r0, r1));
        hw[p] = (uint)__bfloat16_as_ushort(h.x) | ((uint)__bfloat16_as_ushort(h.y) << 16);
        lw[p] = (uint)__bfloat16_as_ushort(l.x) | ((uint)__bfloat16_as_ushort(l.y) << 16);
    }
    *(uint4*)hiP = make_uint4(hw[0], hw[1], hw[2], hw[3]);
    *(uint4*)loP = make_uint4(lw[0], lw[1], lw[2], lw[3]);
}

__device__ __forceinline__ void ld8(const float* p, float* dst) {
    const float4 a = *(const float4*)p;
    const float4 b = *(const float4*)(p + 4);
    dst[0] = a.x; dst[1] = a.y; dst[2] = a.z; dst[3] = a.w;
    dst[4] = b.x; dst[5] = b.y; dst[6] = b.z; dst[7] = b.w;
}

// Kernel A (1-wave blocks, ZERO barriers): 16i x 16j pair tile x 16 t-steps.
// 4096 blocks = 64 tiles x 64 chunks, XCD-grouped (linearID%8 == cz%8), ~8/CU.
// Wave stages its own 32 rows (4 streams x 8 rows) into wave-private LDS;
// intra-wave ds ordering via lgkmcnt only -> no straggler convoy (R9 lesson:
// the per-step __syncthreads was the 2.1 TB/s "ceiling", not memory).
// WP=1: bf16-packed history -> W[cz][pair] (512B-contiguous 16-lane spans).
template<int WP>
__global__ __launch_bounds__(64, 2) void zchunk1w(const float* __restrict__ X,
                                                  const float* __restrict__ Y,
                                                  float* __restrict__ dstF,
                                                  uint*  __restrict__ Wp,
                                                  float* __restrict__ P)
{
    __shared__ __align__(16) ushort smXhi[2][16 * 64], smXlo[2][16 * 64];  // 8 KB
    __shared__ __align__(16) ushort smYhi[2][16 * 64], smYlo[2][16 * 64];  // 8 KB

    // swizzled decode: L = (cz&7) + 8*(tile + 64*(cz>>3))
    const int L    = (int)blockIdx.x;            // 0..4095
    const int tile = (L >> 3) & 63;              // 0..63
    const int cz   = ((L >> 9) << 3) | (L & 7);  // 0..63
    const int i0 = (tile & 7) * 16;
    const int j0 = (tile >> 3) * 16;
    const int t0 = cz * LCH;
    const int lane = (int)threadIdx.x;           // 0..63
    const int quad = lane >> 4, l15 = lane & 15;

    // staging: 4 streams x 8 rows; lane covers (srow, sseg) of each stream
    const int srow = lane >> 3;          // 0..7
    const int sseg = lane & 7;           // 0..7
    const float* gx0 = X + (size_t)(i0 + srow)     * TT * DDIM + sseg * 8;
    const float* gx1 = X + (size_t)(i0 + srow + 8) * TT * DDIM + sseg * 8;
    const float* gy0 = Y + (size_t)(j0 + srow)     * TT * DDIM + sseg * 8;
    const float* gy1 = Y + (size_t)(j0 + srow + 8) * TT * DDIM + sseg * 8;

    const int eA = sidxE(srow,     sseg * 8);    // LDS slot, rows 0..7
    const int eB = sidxE(srow + 8, sseg * 8);    // LDS slot, rows 8..15

    float cx0[8], cx1[8], cy0[8], cy1[8];              // slice t0+h values
    float rx0[2][8], rx1[2][8], ry0[2][8], ry1[2][8];  // 2-deep prefetch ring
    {
        const int sa = (t0 == 0) ? 0 : (t0 - 1);
        float p0[8], p1[8], p2[8], p3[8], d[8];
        ld8(gx0 + (size_t)t0 * DDIM, cx0);
        ld8(gx1 + (size_t)t0 * DDIM, cx1);
        ld8(gy0 + (size_t)t0 * DDIM, cy0);
        ld8(gy1 + (size_t)t0 * DDIM, cy1);
        ld8(gx0 + (size_t)sa * DDIM, p0);
        ld8(gx1 + (size_t)sa * DDIM, p1);
        ld8(gy0 + (size_t)sa * DDIM, p2);
        ld8(gy1 + (size_t)sa * DDIM, p3);
        ld8(gx0 + (size_t)(t0 + 1) * DDIM, rx0[1]);    // slice t0+1 -> set 1
        ld8(gx1 + (size_t)(t0 + 1) * DDIM, rx1[1]);
        ld8(gy0 + (size_t)(t0 + 1) * DDIM, ry0[1]);
        ld8(gy1 + (size_t)(t0 + 1) * DDIM, ry1[1]);

#pragma unroll
        for (int k = 0; k < 8; ++k) d[k] = cx0[k] - p0[k];
        cvt_store(&smXhi[0][eA], &smXlo[0][eA], d);
#pragma unroll
        for (int k = 0; k < 8; ++k) d[k] = cx1[k] - p1[k];
        cvt_store(&smXhi[0][eB], &smXlo[0][eB], d);
#pragma unroll
        for (int k = 0; k < 8; ++k) d[k] = cy0[k] - p2[k];
        cvt_store(&smYhi[0][eA], &smYlo[0][eA], d);
#pragma unroll
        for (int k = 0; k < 8; ++k) d[k] = cy1[k] - p3[k];
        cvt_store(&smYhi[0][eB], &smYlo[0][eB], d);
    }

    float cum[4];
    uint  histP[4][8];                  // bf16-packed 16-step history (static-indexed)
#pragma unroll
    for (int r = 0; r < 4; ++r) cum[r] = 1.f;

#pragma unroll
    for (int h = 0; h < LCH; ++h) {
        const int cur = h & 1;

        if (h + 2 < LCH) {              // prefetch slice t0+h+2 into ring set h&1
            const size_t u = (size_t)(t0 + h + 2) * DDIM;
            ld8(gx0 + u, rx0[h & 1]); ld8(gx1 + u, rx1[h & 1]);
            ld8(gy0 + u, ry0[h & 1]); ld8(gy1 + u, ry1[h & 1]);
        }

        short8 aHi[2], aLo[2], bHi[2], bLo[2];
#pragma unroll
        for (int kk = 0; kk < 2; ++kk) {
            const int e = sidxE(l15, kk * 32 + quad * 8);
            aHi[kk] = *(const short8*)&smXhi[cur][e];
            aLo[kk] = *(const short8*)&smXlo[cur][e];
            bHi[kk] = *(const short8*)&smYhi[cur][e];
            bLo[kk] = *(const short8*)&smYlo[cur][e];
        }

        floatx4 acc = {0.f, 0.f, 0.f, 0.f};
#pragma unroll
        for (int kk = 0; kk < 2; ++kk) {
            acc = __builtin_amdgcn_mfma_f32_16x16x32_bf16(aLo[kk], bHi[kk], acc, 0, 0, 0);
            acc = __builtin_amdgcn_mfma_f32_16x16x32_bf16(aHi[kk], bLo[kk], acc, 0, 0, 0);
            acc = __builtin_amdgcn_mfma_f32_16x16x32_bf16(aHi[kk], bHi[kk], acc, 0, 0, 0);
        }
#pragma unroll
        for (int r = 0; r < 4; ++r) {
            cum[r] *= fmaf(acc[r], DT_INV, 1.f);
            const uint hb = (uint)f2bf(cum[r]);
            if ((h & 1) == 0) histP[r][h >> 1] = hb;
            else              histP[r][h >> 1] |= (hb << 16);
        }

        if (h + 1 < LCH) {              // stage next step's diffs (wave-private, no barrier)
            const int nsel = (h + 1) & 1;
            const int nb   = cur ^ 1;
            float d[8];
#pragma unroll
            for (int k = 0; k < 8; ++k) d[k] = rx0[nsel][k] - cx0[k];
            cvt_store(&smXhi[nb][eA], &smXlo[nb][eA], d);
#pragma unroll
            for (int k = 0; k < 8; ++k) d[k] = rx1[nsel][k] - cx1[k];
            cvt_store(&smXhi[nb][eB], &smXlo[nb][eB], d);
#pragma unroll
            for (int k = 0; k < 8; ++k) d[k] = ry0[nsel][k] - cy0[k];
            cvt_store(&smYhi[nb][eA], &smYlo[nb][eA], d);
#pragma unroll
            for (int k = 0; k < 8; ++k) d[k] = ry1[nsel][k] - cy1[k];
            cvt_store(&smYhi[nb][eB], &smYlo[nb][eB], d);
#pragma unroll
            for (int k = 0; k < 8; ++k) {
                cx0[k] = rx0[nsel][k]; cx1[k] = rx1[nsel][k];
                cy0[k] = ry0[nsel][k]; cy1[k] = ry1[nsel][k];
            }
        }
    }

    // Epilogue: fp32 chunk totals + bf16-packed history (32B/pair -> W).
#pragma unroll
    for (int r = 0; r < 4; ++r) {
        const int pair = (i0 + quad * 4 + r) * BX + (j0 + l15);
        P[(size_t)cz * NPAIR + pair] = cum[r];
        if (WP) {
            uint* o = Wp + ((size_t)cz * NPAIR + pair) * 8;   // 8 uints = 32B
            *(uint4*)o       = make_uint4(histP[r][0], histP[r][1], histP[r][2], histP[r][3]);
            *(uint4*)(o + 4) = make_uint4(histP[r][4], histP[r][5], histP[r][6], histP[r][7]);
        } else {
            float* o = dstF + (size_t)pair * TT + t0;
#pragma unroll
            for (int q = 0; q < 4; ++q) {
                const uint u0 = histP[r][2 * q];
                const uint u1 = histP[r][2 * q + 1];
                *(float4*)(o + q * 4) = make_float4(
                    __builtin_bit_cast(float, u0 << 16),
                    __builtin_bit_cast(float, u0 & 0xffff0000u),
                    __builtin_bit_cast(float, u1 << 16),
                    __builtin_bit_cast(float, u1 & 0xffff0000u));
            }
        }
    }
}

// Kernel B (bf16-W): block = 16 pairs, 1024 blocks. (verified R9 structure)
// Phase 1: parallel exclusive chunk-prefix -> pf[64][pair].
// Phase 2a: waves load W tile (512B-contiguous per instruction) -> LDS.
// Phase 2b: 16 rows; each wave stores 1KB contiguous out (lines complete).
__global__ __launch_bounds__(256) void scanscale_w(float* __restrict__ out,
                                                   const uint* __restrict__ W,
                                                   const float* __restrict__ P)
{
    __shared__ uint2 tileW[NCH * 65];   // [c][pr*4+tb] padded: 33.3 KB
    __shared__ float pf[NCH][17];       // [chunk][pair] padded
    __shared__ float tot[16][17];       // [seg][pair]

    const int p0  = (int)blockIdx.x * 16;
    const int tid = (int)threadIdx.x;
    const int p   = tid & 15;           // pair 0..15
    const int seg = tid >> 4;           // 0..15 (chunks seg*4..+3)

    float v[4], e[4];
#pragma unroll
    for (int k = 0; k < 4; ++k)
        v[k] = P[(size_t)(seg * 4 + k) * NPAIR + p0 + p];
    e[0] = 1.f;
#pragma unroll
    for (int k = 1; k < 4; ++k) e[k] = e[k - 1] * v[k - 1];
    tot[seg][p] = e[3] * v[3];
    __syncthreads();

    float base = 1.f;
#pragma unroll
    for (int q = 0; q < 15; ++q)
        if (q < seg) base *= tot[q][p];
#pragma unroll
    for (int k = 0; k < 4; ++k)
        pf[seg * 4 + k][p] = base * e[k];

    // Phase 2a: W -> LDS. Wave wv: chunks wv*16..+15; lane: pr=l>>2, tb=l&3.
    const int wv = tid >> 6, l = tid & 63;
    const int pr = l >> 2, tb = l & 3;
#pragma unroll
    for (int k = 0; k < 16; ++k) {
        const int c = wv * 16 + k;
        tileW[c * 65 + pr * 4 + tb] =
            *(const uint2*)(W + ((size_t)c * NPAIR + p0 + pr) * 8 + tb * 2);
    }
    __syncthreads();

    // Phase 2b: 16 rows; thread tid -> t=tid*4, c=tid>>2, q=tid&3.
    const int c2 = tid >> 2, q2 = tid & 3;
#pragma unroll 2
    for (int r = 0; r < 16; ++r) {
        const uint2 u = tileW[c2 * 65 + r * 4 + q2];
        const float f = pf[c2][r];
        *(float4*)(out + (size_t)(p0 + r) * TT + tid * 4) = make_float4(
            __builtin_bit_cast(float, u.x << 16) * f,
            __builtin_bit_cast(float, u.x & 0xffff0000u) * f,
            __builtin_bit_cast(float, u.y << 16) * f,
            __builtin_bit_cast(float, u.y & 0xffff0000u) * f);
    }
}

// Legacy fallback kernel B: scan+RMW-scale of out in place.
__global__ __launch_bounds__(256) void scanscale_kernel(float* __restrict__ out,
                                                        const float* __restrict__ P)
{
    __shared__ float pf[16][NCH];       // 4 KB
    const int p0  = (int)blockIdx.x * 16;
    const int tid = (int)threadIdx.x;

    if (tid < 16) {
        const int p = p0 + tid;
        float run = 1.f;
#pragma unroll 4
        for (int c = 0; c < NCH; ++c) {
            pf[tid][c] = run;
            run *= P[(size_t)c * NPAIR + p];
        }
    }
    __syncthreads();

    const int pp  = tid >> 4;
    const int col = tid & 15;
    float* row = out + (size_t)(p0 + pp) * TT;
#pragma unroll
    for (int seg = 0; seg < 16; ++seg) {
        const int t = seg * 64 + col * 4;
        const float f = pf[pp][t >> 4];
        float4 v = *(float4*)(row + t);
        v.x *= f; v.y *= f; v.z *= f; v.w *= f;
        *(float4*)(row + t) = v;
    }
}

extern "C" void kernel_launch(void* const* d_in, const int* in_sizes, int n_in,
                              void* d_out, int out_size, void* d_ws, size_t ws_size,
                              hipStream_t stream)
{
    const float* X = (const float*)d_in[0];
    const float* Y = (const float*)d_in[1];
    float* out = (float*)d_out;
    float* P   = (float*)d_ws;                          // 4 MB
    uint*  W   = (uint*)((float*)d_ws + (size_t)NCH * NPAIR);  // 32 MB bf16-packed

    const size_t need = (size_t)NCH * NPAIR * (4 + 32); // P + W
    if (ws_size >= need) {
        zchunk1w<1><<<dim3(4096), 64, 0, stream>>>(X, Y, out, W, P);
        scanscale_w<<<dim3(NPAIR / 16), 256, 0, stream>>>(out, W, P);
    } else {
        zchunk1w<0><<<dim3(4096), 64, 0, stream>>>(X, Y, out, W, P);
        scanscale_kernel<<<dim3(NPAIR / 16), 256, 0, stream>>>(out, P);
    }
}